// Round 1
// baseline (199.759 us; speedup 1.0000x reference)
//
#include <hip/hip_runtime.h>
#include <hip/hip_bf16.h>
#include <math.h>

// Problem constants (reference: B=8, H=W=512)
#define Bsz    8
#define Wdim   512
#define HWv    (512 * 512)       // 262144 = 2^18
#define LOG2HW 18
#define NIMG   16                // {bg(0..7), fg(8..15)}
#define TILE   64                // 64x64 tiles -> 8x8 = 64 tiles per image
#define TPIX   (TILE * TILE)     // 4096

// ws layout (int32 units):
//   [0, NIMG*HWv)            labels: pixel -> tile root (in-tile) or -1;
//                            tile-root slots -> final root after k_flatten
//   [NIMG*HWv, 2*NIMG*HWv)   areas: tile roots hold partials; final roots
//                            hold totals after k_flatten; 0 elsewhere
//   [2*NIMG*HWv, +16)        per-image max area
//   then (8-byte aligned):   double sums[2]; int counts[2]
//   then: u64 bitsBG[8*4096]; u64 bitsFG[8*4096]   (keep-verdict bitmasks)

// ---------------- union-find (atomicMin only: parents monotone decreasing,
// links point to smaller index => lock-free correct). ----------------
__device__ __forceinline__ int uf_find(int* L, int x) {
  int p = L[x];
  while (p != x) {
    int gp = L[p];
    if (gp != p) atomicMin(&L[x], gp);  // grandparent compression (monotone)
    x = gp;
    p = L[x];
  }
  return x;
}

// Read-only find: no compression writes.
__device__ __forceinline__ int find_ro(const int* __restrict__ L, int x) {
  int p = L[x];
  while (p != x) { x = p; p = L[x]; }
  return x;
}

__device__ __forceinline__ void uf_union(int* L, int a, int b) {
  a = uf_find(L, a);
  b = uf_find(L, b);
  while (a != b) {
    if (a < b) { int t = a; a = b; b = t; }  // ensure a > b
    int old = atomicMin(&L[a], b);
    if (old == a) return;  // linked a -> b
    a = old;               // parent already lowered; keep merging
  }
}

// ---------------- kernels ----------------

// Per-tile CCL in LDS, run-based: a wave == one 64-px row. Pixels link
// directly to their run start (ballot, no atomics); vertical unions only at
// the leftmost pixel of each overlap segment. Finds are PER-RUN (run-start
// lanes only); other lanes take the root via shuffle. 1024 threads/block:
// 16 resident waves per tile to overlap the LDS chains.
__global__ __launch_bounds__(1024) void k_local(const float* __restrict__ cams,
                                                int* __restrict__ labels,
                                                int* __restrict__ areas) {
  int img  = blockIdx.x >> 6;          // 0..15
  int tile = blockIdx.x & 63;          // 8x8 tiles
  int tY = tile >> 3, tX = tile & 7;
  int b = img & 7;
  bool fg = (img & 8) != 0;
  int gbase = img << LOG2HW;
  int oy = tY * TILE, ox = tX * TILE;
  int lane = threadIdx.x & 63;

  __shared__ int P[TPIX];              // parents, 16 KB
  __shared__ int A[TPIX];              // local areas, 16 KB

  // pass 1: mask load + per-row run-start init (wave covers exactly one row)
  #pragma unroll
  for (int it = 0; it < 4; ++it) {
    int i  = it * 1024 + threadIdx.x;  // i & 63 == lane
    int ly = i >> 6;
    float c = cams[(b << LOG2HW) + ((oy + ly) << 9) + (ox + lane)];
    bool m = fg ? (c > 0.6f) : (c >= 0.2f);
    unsigned long long bm = __ballot(m);
    int par = -1;
    if (m) {
      unsigned long long below = (1ULL << lane) - 1ULL;
      unsigned long long z = (~bm) & below;       // zeros below this lane
      int rs = z ? (64 - __clzll(z)) : 0;          // run start = highest zero + 1
      par = (ly << 6) + rs;
    }
    P[i] = par;
    A[i] = 0;
  }
  __syncthreads();

  // pass 2: vertical unions, one per overlap segment (dedup via west pair)
  #pragma unroll
  for (int it = 0; it < 4; ++it) {
    int i = it * 1024 + threadIdx.x;
    if (i >= TILE && P[i] >= 0 && P[i - TILE] >= 0) {
      bool skip = (lane > 0) && (P[i - 1] >= 0) && (P[i - TILE - 1] >= 0);
      if (!skip) uf_union(P, i, i - TILE);
    }
  }
  __syncthreads();

  // pass 3: PER-RUN find + shuffle broadcast + per-run area add.
  #pragma unroll
  for (int it = 0; it < 4; ++it) {
    int i = it * 1024 + threadIdx.x;
    bool m = P[i] >= 0;
    unsigned long long bm = __ballot(m);
    int rs = 0;
    if (m) {
      unsigned long long below = (1ULL << lane) - 1ULL;
      unsigned long long z = (~bm) & below;
      rs = z ? (64 - __clzll(z)) : 0;
    }
    bool isStart = m && (rs == lane);
    int r = -1;
    if (isStart) r = find_ro(P, i);
    int root = __shfl(r, rs);          // valid wherever m
    if (m) P[i] = root;
    if (isStart) {
      unsigned long long t = (~bm) >> lane;
      int runlen = t ? (__ffsll((long long)t) - 1) : (64 - lane);
      atomicAdd(&A[root], runlen);
    }
  }
  __syncthreads();

  // pass 4: pure-read write-out: labels (global idx of tile root, fully
  // compressed) + root partial areas
  #pragma unroll
  for (int it = 0; it < 4; ++it) {
    int i  = it * 1024 + threadIdx.x;
    int ly = i >> 6;
    int g  = ((oy + ly) << 9) + (ox + lane);
    int p  = P[i];
    int lab = -1;
    if (p >= 0) lab = ((oy + (p >> 6)) << 9) + (ox + (p & 63));
    labels[gbase + g] = lab;
    areas[gbase + g]  = (p == i) ? A[i] : 0;
  }
}

// Merge across tile boundaries, one union per contiguous overlap segment.
// Also folds the tiny init (maxa/sums/counts) into block 0.
__global__ void k_border(int* __restrict__ labels, int* __restrict__ maxa,
                         double* __restrict__ sums, int* __restrict__ counts) {
  if (blockIdx.x == 0) {
    if (threadIdx.x < NIMG) maxa[threadIdx.x] = 0;
    if (threadIdx.x < 2) { sums[threadIdx.x] = 0.0; counts[threadIdx.x] = 0; }
  }
  const int per_img = 14 * Wdim;       // 7168
  int t = blockIdx.x * blockDim.x + threadIdx.x;
  if (t >= NIMG * per_img) return;
  int img = t / per_img;
  int r   = t - img * per_img;
  int k = r >> 9, j = r & (Wdim - 1);
  int* L = labels + (img << LOG2HW);
  // mask-ness (>=0 vs -1) of label slots is immutable here => dedup stable.
  if (k < 7) {                          // vertical border: x = 64k+63, union east
    int x = TILE * k + (TILE - 1);
    int p = (j << 9) + x, q = p + 1;    // j = y
    if (L[p] >= 0 && L[q] >= 0) {
      bool skip = (j > 0) && (L[p - Wdim] >= 0) && (L[q - Wdim] >= 0);
      if (!skip) uf_union(L, p, q);
    }
  } else {                              // horizontal border: y = 64(k-7)+63, union south
    int y = TILE * (k - 7) + (TILE - 1);
    int p = (y << 9) + j, q = p + Wdim; // j = x
    if (L[p] >= 0 && L[q] >= 0) {
      bool skip = (j > 0) && (L[p - 1] >= 0) && (L[q - 1] >= 0);
      if (!skip) uf_union(L, p, q);
    }
  }
}

// PUSH-ONLY flatten: only tile-root slots (area>0, ~4% of slots) do work:
// find final root, rewrite OWN label slot to it, push partial area with a
// NON-RETURNING atomic. Pixel labels untouched. Stale partials at non-final
// roots are <= component totals, so k_max is unaffected.
__global__ void k_flatten(int* __restrict__ labels, int* __restrict__ areas) {
  int t = blockIdx.x * blockDim.x + threadIdx.x;
  int idx0 = t << 2;
  int4 ar = *(const int4*)&areas[idx0];
  if ((ar.x | ar.y | ar.z | ar.w) <= 0) return;   // all >= 0
  int img  = idx0 >> LOG2HW;
  int base = img << LOG2HW;
  int* L = labels + base;
  int self0 = idx0 - base;
  int4 lab = *(const int4*)&labels[idx0];
  if (ar.x > 0) { int r = find_ro(L, lab.x); L[self0]     = r; if (r != self0)     atomicAdd(&areas[base + r], ar.x); }
  if (ar.y > 0) { int r = find_ro(L, lab.y); L[self0 + 1] = r; if (r != self0 + 1) atomicAdd(&areas[base + r], ar.y); }
  if (ar.z > 0) { int r = find_ro(L, lab.z); L[self0 + 2] = r; if (r != self0 + 2) atomicAdd(&areas[base + r], ar.z); }
  if (ar.w > 0) { int r = find_ro(L, lab.w); L[self0 + 3] = r; if (r != self0 + 3) atomicAdd(&areas[base + r], ar.w); }
}

// Per-image max area: 16 blocks/image, 16 int4 grid-stride reads per thread,
// 1 atomicMax per block.
__global__ void k_max(const int* __restrict__ areas, int* __restrict__ maxa) {
  int img = blockIdx.x >> 4;           // 16 blocks per image
  int seg = blockIdx.x & 15;
  const int4* a4 = (const int4*)(areas + (img << LOG2HW));
  int base = seg * (HWv / 4 / 16);     // 4096 int4 per block
  int m = 0;
  #pragma unroll
  for (int k = 0; k < 16; ++k) {
    int4 v = a4[base + k * 256 + threadIdx.x];
    m = max(m, max(max(v.x, v.y), max(v.z, v.w)));
  }
  #pragma unroll
  for (int off = 32; off > 0; off >>= 1)
    m = max(m, __shfl_down(m, off));
  __shared__ int lm[4];
  int wave = threadIdx.x >> 6;
  if ((threadIdx.x & 63) == 0) lm[wave] = m;
  __syncthreads();
  if (threadIdx.x == 0) {
    int bm = max(max(lm[0], lm[1]), max(lm[2], lm[3]));
    if (bm > 0) atomicMax(&maxa[img], bm);
  }
}

// NEW: materialize per-pixel keep-verdicts as bitmasks (1 bit/px), decoupling
// the gather-chain from the preds stream. Same tile/LDS structure as the old
// k_keepce phase 1: one gather per ROOT slot builds an LDS verdict table;
// per-pixel resolution is an LDS read; bits packed per 64-px row via
// shfl_xor-OR and stored as one u64 word per row.
__global__ __launch_bounds__(1024) void k_verdict(const int* __restrict__ labels,
                                                  const int* __restrict__ areas,
                                                  const int* __restrict__ maxa,
                                                  unsigned long long* __restrict__ bitsBG,
                                                  unsigned long long* __restrict__ bitsFG) {
  int img  = blockIdx.x >> 6;          // 0..15
  int tile = blockIdx.x & 63;
  int tY = tile >> 3, tX = tile & 7;
  int oy = tY * TILE, ox = tX * TILE;
  int base = img << LOG2HW;
  int mx = maxa[img];

  __shared__ int V[TPIX];              // verdict table (root slots only), 16 KB

  int i  = threadIdx.x << 2;           // in-tile index of 4-px group
  int ly = i >> 6, lx = i & 63;
  int g  = ((oy + ly) << 9) + (ox + lx);    // in-image index
  int4 lb = *(const int4*)&labels[base + g];
  int4 ar = *(const int4*)&areas[base + g];
  // root slots: their label already holds the FINAL root (k_flatten).
  if (ar.x > 0) { V[i + 0] = (2 * areas[base + lb.x] > mx); lb.x = g + 0; }
  if (ar.y > 0) { V[i + 1] = (2 * areas[base + lb.y] > mx); lb.y = g + 1; }
  if (ar.z > 0) { V[i + 2] = (2 * areas[base + lb.z] > mx); lb.z = g + 2; }
  if (ar.w > 0) { V[i + 3] = (2 * areas[base + lb.w] > mx); lb.w = g + 3; }
  __syncthreads();

  // per-pixel verdict nibble (bit j = pixel g+j kept)
  int l[4] = {lb.x, lb.y, lb.z, lb.w};
  unsigned nib = 0;
  #pragma unroll
  for (int j = 0; j < 4; ++j) {
    if (l[j] >= 0) {
      int loc = (((l[j] >> 9) & 63) << 6) | (l[j] & 63);
      nib |= (V[loc] ? 1u : 0u) << j;
    }
  }

  // pack: 16 lanes (lane&15) cover one 64-px row -> one u64 word.
  int lane = threadIdx.x & 63;
  unsigned long long w = (unsigned long long)nib << ((lane & 15) << 2);
  w |= __shfl_xor(w, 1);
  w |= __shfl_xor(w, 2);
  w |= __shfl_xor(w, 4);
  w |= __shfl_xor(w, 8);
  if ((lane & 15) == 0) {
    int wordIdx = ((oy + ly) << 3) + tX;    // (row*512 + ox) / 64
    unsigned long long* dst = (img < 8) ? (bitsBG + ((img & 7) << 12))
                                        : (bitsFG + ((img & 7) << 12));
    dst[wordIdx] = w;
  }
}

// NEW: pure-streaming CE. No LDS table, no pre-compute barrier, no gathers:
// each thread owns one float4 pixel-group (g4) for images {b0, b0+4} and all
// 3 preds (6 float4-pair loads), verdicts come from 4 cached bit-words.
// Counts are accumulated ONCE per pixel (not x3), matching the old semantics.
__global__ __launch_bounds__(256) void k_ce(const float* __restrict__ preds,
                                            const unsigned long long* __restrict__ bitsBG,
                                            const unsigned long long* __restrict__ bitsFG,
                                            double* __restrict__ sums,
                                            int* __restrict__ counts) {
  int tid = blockIdx.x * 256 + threadIdx.x;   // [0, 262144)
  int g4  = tid & 65535;                      // float4 group within image
  int b0  = tid >> 16;                        // 0..3 -> handles b0 and b0+4
  int wi  = g4 >> 4;                          // u64 word index within image
  int sh  = (g4 & 15) << 2;                   // nibble shift within word

  unsigned long long wB0 = bitsBG[(b0 << 12) + wi];
  unsigned long long wF0 = bitsFG[(b0 << 12) + wi];
  unsigned long long wB1 = bitsBG[((b0 + 4) << 12) + wi];
  unsigned long long wF1 = bitsFG[((b0 + 4) << 12) + wi];
  unsigned nB[2] = { (unsigned)(wB0 >> sh) & 15u, (unsigned)(wB1 >> sh) & 15u };
  unsigned nF[2] = { (unsigned)(wF0 >> sh) & 15u, (unsigned)(wF1 >> sh) & 15u };

  int cf = __popc(nF[0]) + __popc(nF[1]);               // fg valid = kept
  int cb = 8 - __popc(nB[0]) - __popc(nB[1]);           // bg valid = NOT kept

  float sfg = 0.f, sbg = 0.f;
  int px = g4 << 2;
  #pragma unroll
  for (int p = 0; p < 3; ++p) {
    #pragma unroll
    for (int bi = 0; bi < 2; ++bi) {
      int b = b0 + 4 * bi;
      const float* pb = preds + ((size_t)((p * Bsz + b) * 2) << LOG2HW);
      float4 A0 = *(const float4*)&pb[px];
      float4 A1 = *(const float4*)&pb[HWv + px];
      float d[4] = {A0.x - A1.x, A0.y - A1.y, A0.z - A1.z, A0.w - A1.w};
      #pragma unroll
      for (int j = 0; j < 4; ++j) {
        float sp = logf(1.f + expf(-fabsf(d[j])));
        bool vfj = (nF[bi] >> j) & 1u;
        bool vbj = !((nB[bi] >> j) & 1u);
        sfg += vfj ? (fmaxf(d[j], 0.f) + sp) : 0.f;
        sbg += vbj ? (fmaxf(-d[j], 0.f) + sp) : 0.f;
      }
    }
  }

  // block reduction: wave64 shuffle -> LDS -> 4 atomics/block
  #pragma unroll
  for (int off = 32; off > 0; off >>= 1) {
    sfg += __shfl_down(sfg, off);
    sbg += __shfl_down(sbg, off);
    cf  += __shfl_down(cf, off);
    cb  += __shfl_down(cb, off);
  }
  __shared__ float lsf[4], lsb[4];
  __shared__ int   lcf[4], lcb[4];
  int wave = threadIdx.x >> 6;
  if ((threadIdx.x & 63) == 0) {
    lsf[wave] = sfg; lsb[wave] = sbg; lcf[wave] = cf; lcb[wave] = cb;
  }
  __syncthreads();
  if (threadIdx.x == 0) {
    float tf = lsf[0] + lsf[1] + lsf[2] + lsf[3];
    float tb = lsb[0] + lsb[1] + lsb[2] + lsb[3];
    int af_ = lcf[0] + lcf[1] + lcf[2] + lcf[3];
    int ab_ = lcb[0] + lcb[1] + lcb[2] + lcb[3];
    atomicAdd(&sums[0], (double)tf);
    atomicAdd(&sums[1], (double)tb);
    atomicAdd(&counts[0], af_);
    atomicAdd(&counts[1], ab_);
  }
}

__global__ void k_final(const double* __restrict__ sums, const int* __restrict__ counts,
                        float* __restrict__ out) {
  if (threadIdx.x == 0 && blockIdx.x == 0) {
    double df = counts[0] > 0 ? (double)counts[0] : 1.0;
    double db = counts[1] > 0 ? (double)counts[1] : 1.0;
    out[0] = (float)(sums[0] / df + sums[1] / db);
  }
}

extern "C" void kernel_launch(void* const* d_in, const int* in_sizes, int n_in,
                              void* d_out, int out_size, void* d_ws, size_t ws_size,
                              hipStream_t stream) {
  (void)in_sizes; (void)n_in; (void)out_size; (void)ws_size;
  const float* preds = (const float*)d_in[0];  // [3,8,2,512,512] f32
  const float* cams  = (const float*)d_in[1];  // [8,1,512,512]  f32
  float* out = (float*)d_out;                  // scalar f32

  int* labels = (int*)d_ws;
  int* areas  = labels + NIMG * HWv;
  int* maxa   = areas + NIMG * HWv;
  double* sums = (double*)(maxa + 16);
  int* counts  = (int*)(sums + 2);
  unsigned long long* bitsBG = (unsigned long long*)(counts + 2);  // 8-aligned (+88 B)
  unsigned long long* bitsFG = bitsBG + Bsz * (HWv / 64);          // 256 KB each

  const int threads = 256;

  k_local  <<<NIMG * 64, 1024, 0, stream>>>(cams, labels, areas);
  k_border <<<(NIMG * 14 * Wdim + threads - 1) / threads, threads, 0, stream>>>(labels, maxa, sums, counts);
  k_flatten<<<NIMG * HWv / (threads * 4), threads, 0, stream>>>(labels, areas);
  k_max    <<<NIMG * 16, threads, 0, stream>>>(areas, maxa);
  k_verdict<<<NIMG * 64, 1024, 0, stream>>>(labels, areas, maxa, bitsBG, bitsFG);
  k_ce     <<<1024, 256, 0, stream>>>(preds, bitsBG, bitsFG, sums, counts);
  k_final  <<<1, 64, 0, stream>>>(sums, counts, out);
}

// Round 2
// 154.967 us; speedup vs baseline: 1.2890x; 1.2890x over previous
//
#include <hip/hip_runtime.h>
#include <hip/hip_bf16.h>
#include <math.h>

// Problem constants (reference: B=8, H=W=512)
#define Bsz    8
#define Wdim   512
#define HWv    (512 * 512)       // 262144 = 2^18
#define LOG2HW 18
#define NIMG   16                // {bg(0..7), fg(8..15)}
#define TILE   64                // 64x64 tiles -> 8x8 = 64 tiles per image
#define TPIX   (TILE * TILE)     // 4096
#define CEBLK  6144              // k_ce blocks: 3 preds * 8 b * 256 blocks
#define CNTBLK 2048              // k_ce blocks with p==0 (count producers)

// ws layout (int32 units):
//   [0, NIMG*HWv)            labels
//   [NIMG*HWv, 2*NIMG*HWv)   areas
//   [2*NIMG*HWv, +16)        per-image max area
//   then (8-byte aligned):   double sums[2]; int counts[2] (legacy, unused)
//   then: u64 bitsBG[8*4096]; u64 bitsFG[8*4096]   (keep-verdict bitmasks)
//   then: float pf[CEBLK]; float pbg[CEBLK]; int pcf[CNTBLK]; int pcb[CNTBLK]

// ---------------- union-find (atomicMin only: parents monotone decreasing,
// links point to smaller index => lock-free correct). ----------------
__device__ __forceinline__ int uf_find(int* L, int x) {
  int p = L[x];
  while (p != x) {
    int gp = L[p];
    if (gp != p) atomicMin(&L[x], gp);  // grandparent compression (monotone)
    x = gp;
    p = L[x];
  }
  return x;
}

// Read-only find: no compression writes.
__device__ __forceinline__ int find_ro(const int* __restrict__ L, int x) {
  int p = L[x];
  while (p != x) { x = p; p = L[x]; }
  return x;
}

__device__ __forceinline__ void uf_union(int* L, int a, int b) {
  a = uf_find(L, a);
  b = uf_find(L, b);
  while (a != b) {
    if (a < b) { int t = a; a = b; b = t; }  // ensure a > b
    int old = atomicMin(&L[a], b);
    if (old == a) return;  // linked a -> b
    a = old;               // parent already lowered; keep merging
  }
}

// ---------------- kernels ----------------

// Per-tile CCL in LDS, run-based: a wave == one 64-px row. Pixels link
// directly to their run start (ballot, no atomics); vertical unions only at
// the leftmost pixel of each overlap segment. Finds are PER-RUN (run-start
// lanes only); other lanes take the root via shuffle. 1024 threads/block:
// 16 resident waves per tile to overlap the LDS chains.
__global__ __launch_bounds__(1024) void k_local(const float* __restrict__ cams,
                                                int* __restrict__ labels,
                                                int* __restrict__ areas) {
  int img  = blockIdx.x >> 6;          // 0..15
  int tile = blockIdx.x & 63;          // 8x8 tiles
  int tY = tile >> 3, tX = tile & 7;
  int b = img & 7;
  bool fg = (img & 8) != 0;
  int gbase = img << LOG2HW;
  int oy = tY * TILE, ox = tX * TILE;
  int lane = threadIdx.x & 63;

  __shared__ int P[TPIX];              // parents, 16 KB
  __shared__ int A[TPIX];              // local areas, 16 KB

  // pass 1: mask load + per-row run-start init (wave covers exactly one row)
  #pragma unroll
  for (int it = 0; it < 4; ++it) {
    int i  = it * 1024 + threadIdx.x;  // i & 63 == lane
    int ly = i >> 6;
    float c = cams[(b << LOG2HW) + ((oy + ly) << 9) + (ox + lane)];
    bool m = fg ? (c > 0.6f) : (c >= 0.2f);
    unsigned long long bm = __ballot(m);
    int par = -1;
    if (m) {
      unsigned long long below = (1ULL << lane) - 1ULL;
      unsigned long long z = (~bm) & below;       // zeros below this lane
      int rs = z ? (64 - __clzll(z)) : 0;          // run start = highest zero + 1
      par = (ly << 6) + rs;
    }
    P[i] = par;
    A[i] = 0;
  }
  __syncthreads();

  // pass 2: vertical unions, one per overlap segment (dedup via west pair)
  #pragma unroll
  for (int it = 0; it < 4; ++it) {
    int i = it * 1024 + threadIdx.x;
    if (i >= TILE && P[i] >= 0 && P[i - TILE] >= 0) {
      bool skip = (lane > 0) && (P[i - 1] >= 0) && (P[i - TILE - 1] >= 0);
      if (!skip) uf_union(P, i, i - TILE);
    }
  }
  __syncthreads();

  // pass 3: PER-RUN find + shuffle broadcast + per-run area add.
  #pragma unroll
  for (int it = 0; it < 4; ++it) {
    int i = it * 1024 + threadIdx.x;
    bool m = P[i] >= 0;
    unsigned long long bm = __ballot(m);
    int rs = 0;
    if (m) {
      unsigned long long below = (1ULL << lane) - 1ULL;
      unsigned long long z = (~bm) & below;
      rs = z ? (64 - __clzll(z)) : 0;
    }
    bool isStart = m && (rs == lane);
    int r = -1;
    if (isStart) r = find_ro(P, i);
    int root = __shfl(r, rs);          // valid wherever m
    if (m) P[i] = root;
    if (isStart) {
      unsigned long long t = (~bm) >> lane;
      int runlen = t ? (__ffsll((long long)t) - 1) : (64 - lane);
      atomicAdd(&A[root], runlen);
    }
  }
  __syncthreads();

  // pass 4: pure-read write-out: labels (global idx of tile root, fully
  // compressed) + root partial areas
  #pragma unroll
  for (int it = 0; it < 4; ++it) {
    int i  = it * 1024 + threadIdx.x;
    int ly = i >> 6;
    int g  = ((oy + ly) << 9) + (ox + lane);
    int p  = P[i];
    int lab = -1;
    if (p >= 0) lab = ((oy + (p >> 6)) << 9) + (ox + (p & 63));
    labels[gbase + g] = lab;
    areas[gbase + g]  = (p == i) ? A[i] : 0;
  }
}

// Merge across tile boundaries, one union per contiguous overlap segment.
// Also folds the tiny init (maxa) into block 0.
__global__ void k_border(int* __restrict__ labels, int* __restrict__ maxa) {
  if (blockIdx.x == 0) {
    if (threadIdx.x < NIMG) maxa[threadIdx.x] = 0;
  }
  const int per_img = 14 * Wdim;       // 7168
  int t = blockIdx.x * blockDim.x + threadIdx.x;
  if (t >= NIMG * per_img) return;
  int img = t / per_img;
  int r   = t - img * per_img;
  int k = r >> 9, j = r & (Wdim - 1);
  int* L = labels + (img << LOG2HW);
  // mask-ness (>=0 vs -1) of label slots is immutable here => dedup stable.
  if (k < 7) {                          // vertical border: x = 64k+63, union east
    int x = TILE * k + (TILE - 1);
    int p = (j << 9) + x, q = p + 1;    // j = y
    if (L[p] >= 0 && L[q] >= 0) {
      bool skip = (j > 0) && (L[p - Wdim] >= 0) && (L[q - Wdim] >= 0);
      if (!skip) uf_union(L, p, q);
    }
  } else {                              // horizontal border: y = 64(k-7)+63, union south
    int y = TILE * (k - 7) + (TILE - 1);
    int p = (y << 9) + j, q = p + Wdim; // j = x
    if (L[p] >= 0 && L[q] >= 0) {
      bool skip = (j > 0) && (L[p - 1] >= 0) && (L[q - 1] >= 0);
      if (!skip) uf_union(L, p, q);
    }
  }
}

// PUSH-ONLY flatten: only tile-root slots (area>0, ~4% of slots) do work:
// find final root, rewrite OWN label slot to it, push partial area with a
// NON-RETURNING atomic. Pixel labels untouched. Stale partials at non-final
// roots are <= component totals, so k_max is unaffected.
__global__ void k_flatten(int* __restrict__ labels, int* __restrict__ areas) {
  int t = blockIdx.x * blockDim.x + threadIdx.x;
  int idx0 = t << 2;
  int4 ar = *(const int4*)&areas[idx0];
  if ((ar.x | ar.y | ar.z | ar.w) <= 0) return;   // all >= 0
  int img  = idx0 >> LOG2HW;
  int base = img << LOG2HW;
  int* L = labels + base;
  int self0 = idx0 - base;
  int4 lab = *(const int4*)&labels[idx0];
  if (ar.x > 0) { int r = find_ro(L, lab.x); L[self0]     = r; if (r != self0)     atomicAdd(&areas[base + r], ar.x); }
  if (ar.y > 0) { int r = find_ro(L, lab.y); L[self0 + 1] = r; if (r != self0 + 1) atomicAdd(&areas[base + r], ar.y); }
  if (ar.z > 0) { int r = find_ro(L, lab.z); L[self0 + 2] = r; if (r != self0 + 2) atomicAdd(&areas[base + r], ar.z); }
  if (ar.w > 0) { int r = find_ro(L, lab.w); L[self0 + 3] = r; if (r != self0 + 3) atomicAdd(&areas[base + r], ar.w); }
}

// Per-image max area: 16 blocks/image, 16 int4 grid-stride reads per thread,
// 1 atomicMax per block.
__global__ void k_max(const int* __restrict__ areas, int* __restrict__ maxa) {
  int img = blockIdx.x >> 4;           // 16 blocks per image
  int seg = blockIdx.x & 15;
  const int4* a4 = (const int4*)(areas + (img << LOG2HW));
  int base = seg * (HWv / 4 / 16);     // 4096 int4 per block
  int m = 0;
  #pragma unroll
  for (int k = 0; k < 16; ++k) {
    int4 v = a4[base + k * 256 + threadIdx.x];
    m = max(m, max(max(v.x, v.y), max(v.z, v.w)));
  }
  #pragma unroll
  for (int off = 32; off > 0; off >>= 1)
    m = max(m, __shfl_down(m, off));
  __shared__ int lm[4];
  int wave = threadIdx.x >> 6;
  if ((threadIdx.x & 63) == 0) lm[wave] = m;
  __syncthreads();
  if (threadIdx.x == 0) {
    int bm = max(max(lm[0], lm[1]), max(lm[2], lm[3]));
    if (bm > 0) atomicMax(&maxa[img], bm);
  }
}

// Materialize per-pixel keep-verdicts as bitmasks (1 bit/px). Same tile/LDS
// structure as the CCL kernels: one gather per ROOT slot builds an LDS
// verdict table; per-pixel resolution is an LDS read; bits packed per 64-px
// row via shfl_xor-OR and stored as one u64 word per row.
__global__ __launch_bounds__(1024) void k_verdict(const int* __restrict__ labels,
                                                  const int* __restrict__ areas,
                                                  const int* __restrict__ maxa,
                                                  unsigned long long* __restrict__ bitsBG,
                                                  unsigned long long* __restrict__ bitsFG) {
  int img  = blockIdx.x >> 6;          // 0..15
  int tile = blockIdx.x & 63;
  int tY = tile >> 3, tX = tile & 7;
  int oy = tY * TILE, ox = tX * TILE;
  int base = img << LOG2HW;
  int mx = maxa[img];

  __shared__ int V[TPIX];              // verdict table (root slots only), 16 KB

  int i  = threadIdx.x << 2;           // in-tile index of 4-px group
  int ly = i >> 6, lx = i & 63;
  int g  = ((oy + ly) << 9) + (ox + lx);    // in-image index
  int4 lb = *(const int4*)&labels[base + g];
  int4 ar = *(const int4*)&areas[base + g];
  // root slots: their label already holds the FINAL root (k_flatten).
  if (ar.x > 0) { V[i + 0] = (2 * areas[base + lb.x] > mx); lb.x = g + 0; }
  if (ar.y > 0) { V[i + 1] = (2 * areas[base + lb.y] > mx); lb.y = g + 1; }
  if (ar.z > 0) { V[i + 2] = (2 * areas[base + lb.z] > mx); lb.z = g + 2; }
  if (ar.w > 0) { V[i + 3] = (2 * areas[base + lb.w] > mx); lb.w = g + 3; }
  __syncthreads();

  // per-pixel verdict nibble (bit j = pixel g+j kept)
  int l[4] = {lb.x, lb.y, lb.z, lb.w};
  unsigned nib = 0;
  #pragma unroll
  for (int j = 0; j < 4; ++j) {
    if (l[j] >= 0) {
      int loc = (((l[j] >> 9) & 63) << 6) | (l[j] & 63);
      nib |= (V[loc] ? 1u : 0u) << j;
    }
  }

  // pack: 16 lanes (lane&15) cover one 64-px row -> one u64 word.
  int lane = threadIdx.x & 63;
  unsigned long long w = (unsigned long long)nib << ((lane & 15) << 2);
  w |= __shfl_xor(w, 1);
  w |= __shfl_xor(w, 2);
  w |= __shfl_xor(w, 4);
  w |= __shfl_xor(w, 8);
  if ((lane & 15) == 0) {
    int wordIdx = ((oy + ly) << 3) + tX;    // (row*512 + ox) / 64
    unsigned long long* dst = (img < 8) ? (bitsBG + ((img & 7) << 12))
                                        : (bitsFG + ((img & 7) << 12));
    dst[wordIdx] = w;
  }
}

// Pure-streaming CE, one thread per (p, b, float4-group): exactly 2 float4
// loads + 2 cached u64 bit-word loads per thread (all issued up front, tiny
// register footprint -> no serialized load chains), 6144 blocks for full TLP.
// Per-block partials to DISTINCT addresses (no same-line atomic contention);
// counts produced only by the p==0 blocks (uniform branch per block).
__global__ __launch_bounds__(256) void k_ce(const float* __restrict__ preds,
                                            const unsigned long long* __restrict__ bitsBG,
                                            const unsigned long long* __restrict__ bitsFG,
                                            float* __restrict__ pf,
                                            float* __restrict__ pbg,
                                            int* __restrict__ pcf,
                                            int* __restrict__ pcb) {
  int tid = blockIdx.x * 256 + threadIdx.x;   // [0, 3*8*65536)
  int g4  = tid & 65535;                      // float4 group within image
  int pb  = tid >> 16;                        // 0..23
  int b   = pb & 7;
  int p   = pb >> 3;                          // 0..2 (uniform per block)

  int wi = (b << 12) + (g4 >> 4);             // u64 word index
  int sh = (g4 & 15) << 2;                    // nibble shift within word
  unsigned nB = (unsigned)(bitsBG[wi] >> sh) & 15u;
  unsigned nF = (unsigned)(bitsFG[wi] >> sh) & 15u;

  const float* pbase = preds + ((size_t)((p * Bsz + b) * 2) << LOG2HW);
  int px = g4 << 2;
  float4 A0 = *(const float4*)&pbase[px];
  float4 A1 = *(const float4*)&pbase[HWv + px];

  float d[4] = {A0.x - A1.x, A0.y - A1.y, A0.z - A1.z, A0.w - A1.w};
  float sfg = 0.f, sbg = 0.f;
  #pragma unroll
  for (int j = 0; j < 4; ++j) {
    float sp = logf(1.f + expf(-fabsf(d[j])));
    bool vfj = (nF >> j) & 1u;
    bool vbj = !((nB >> j) & 1u);
    sfg += vfj ? (fmaxf(d[j], 0.f) + sp) : 0.f;
    sbg += vbj ? (fmaxf(-d[j], 0.f) + sp) : 0.f;
  }
  int cf = __popc(nF);
  int cb = 4 - __popc(nB);

  // block reduction: wave64 shuffle -> LDS -> one partial-write per block
  #pragma unroll
  for (int off = 32; off > 0; off >>= 1) {
    sfg += __shfl_down(sfg, off);
    sbg += __shfl_down(sbg, off);
    cf  += __shfl_down(cf, off);
    cb  += __shfl_down(cb, off);
  }
  __shared__ float lsf[4], lsb[4];
  __shared__ int   lcf[4], lcb[4];
  int wave = threadIdx.x >> 6;
  if ((threadIdx.x & 63) == 0) {
    lsf[wave] = sfg; lsb[wave] = sbg; lcf[wave] = cf; lcb[wave] = cb;
  }
  __syncthreads();
  if (threadIdx.x == 0) {
    pf[blockIdx.x]  = lsf[0] + lsf[1] + lsf[2] + lsf[3];
    pbg[blockIdx.x] = lsb[0] + lsb[1] + lsb[2] + lsb[3];
    if (p == 0) {                       // count each pixel ONCE (p==0 blocks)
      pcf[blockIdx.x] = lcf[0] + lcf[1] + lcf[2] + lcf[3];
      pcb[blockIdx.x] = lcb[0] + lcb[1] + lcb[2] + lcb[3];
    }
  }
}

// Final reduce: 6144x2 float partials + 2048x2 int partials in one block.
__global__ __launch_bounds__(1024) void k_final(const float* __restrict__ pf,
                                                const float* __restrict__ pbg,
                                                const int* __restrict__ pcf,
                                                const int* __restrict__ pcb,
                                                float* __restrict__ out) {
  int t = threadIdx.x;
  double sf = 0.0, sb = 0.0;
  int cf = 0, cb = 0;
  #pragma unroll
  for (int k = 0; k < CEBLK / 1024; ++k) {
    sf += (double)pf[k * 1024 + t];
    sb += (double)pbg[k * 1024 + t];
  }
  #pragma unroll
  for (int k = 0; k < CNTBLK / 1024; ++k) {
    cf += pcf[k * 1024 + t];
    cb += pcb[k * 1024 + t];
  }
  #pragma unroll
  for (int off = 32; off > 0; off >>= 1) {
    sf += __shfl_down(sf, off);
    sb += __shfl_down(sb, off);
    cf += __shfl_down(cf, off);
    cb += __shfl_down(cb, off);
  }
  __shared__ double dsf[16], dsb[16];
  __shared__ int    icf[16], icb[16];
  int wave = t >> 6;
  if ((t & 63) == 0) { dsf[wave] = sf; dsb[wave] = sb; icf[wave] = cf; icb[wave] = cb; }
  __syncthreads();
  if (t == 0) {
    double tf = 0.0, tb = 0.0; int af_ = 0, ab_ = 0;
    #pragma unroll
    for (int w = 0; w < 16; ++w) { tf += dsf[w]; tb += dsb[w]; af_ += icf[w]; ab_ += icb[w]; }
    double df = af_ > 0 ? (double)af_ : 1.0;
    double db = ab_ > 0 ? (double)ab_ : 1.0;
    out[0] = (float)(tf / df + tb / db);
  }
}

extern "C" void kernel_launch(void* const* d_in, const int* in_sizes, int n_in,
                              void* d_out, int out_size, void* d_ws, size_t ws_size,
                              hipStream_t stream) {
  (void)in_sizes; (void)n_in; (void)out_size; (void)ws_size;
  const float* preds = (const float*)d_in[0];  // [3,8,2,512,512] f32
  const float* cams  = (const float*)d_in[1];  // [8,1,512,512]  f32
  float* out = (float*)d_out;                  // scalar f32

  int* labels = (int*)d_ws;
  int* areas  = labels + NIMG * HWv;
  int* maxa   = areas + NIMG * HWv;
  double* sums = (double*)(maxa + 16);         // legacy slot (keeps alignment)
  int* counts  = (int*)(sums + 2);
  unsigned long long* bitsBG = (unsigned long long*)(counts + 2);  // 8-aligned
  unsigned long long* bitsFG = bitsBG + Bsz * (HWv / 64);          // 256 KB each
  float* pf  = (float*)(bitsFG + Bsz * (HWv / 64));
  float* pbg = pf + CEBLK;
  int*   pcf = (int*)(pbg + CEBLK);
  int*   pcb = pcf + CNTBLK;

  const int threads = 256;

  k_local  <<<NIMG * 64, 1024, 0, stream>>>(cams, labels, areas);
  k_border <<<(NIMG * 14 * Wdim + threads - 1) / threads, threads, 0, stream>>>(labels, maxa);
  k_flatten<<<NIMG * HWv / (threads * 4), threads, 0, stream>>>(labels, areas);
  k_max    <<<NIMG * 16, threads, 0, stream>>>(areas, maxa);
  k_verdict<<<NIMG * 64, 1024, 0, stream>>>(labels, areas, maxa, bitsBG, bitsFG);
  k_ce     <<<CEBLK, 256, 0, stream>>>(preds, bitsBG, bitsFG, pf, pbg, pcf, pcb);
  k_final  <<<1, 1024, 0, stream>>>(pf, pbg, pcf, pcb, out);
}